// Round 8
// baseline (2203.991 us; speedup 1.0000x reference)
//
#include <hip/hip_runtime.h>
#include <cstdint>
#include <cstddef>

#define BB 8
#define SS 2
#define TT 512
#define CC 2048
#define ND 1024
#define AD 16384
#define NN 256
#define AN 2048
#define NEGV -1e30f
#define NTH 1024    // fwd block threads
#define NWG 256     // fused grid: 16 den + 32 num + 208 wprep workers
#define BP 17       // arcs per den thread (wave-aligned state partition, <=1088/wave)
#define ADP (BP * 1024)   // transposed meta stream length (17408)
#define WSD 20480   // W' stride per (inst,step): 20 floats/thread (16B-aligned loads)

// guarded online-LSE merge (same rounding class as the passing pk merge)
#define LSE_MERGE(mm, s2, m2, sp) do { \
    const float _d = (m2) - (mm); const float _e = __expf(-fabsf(_d)); \
    if (_d > 0.f) { s2 = s2 * _e + (sp); mm = (m2); } else { s2 += (sp) * _e; } } while (0)

// ---------------------------------------------------------------------------
// num prep: counting sort by dst into chunk-transposed SoA
//   meta = gidx | dst<<16 (two-choice bank-balanced dual-copy gather index)
//   pxi/wcsr: CSR-order pdf and weight for the W' precompute
//   pbeg/padj: partial-slot tables for the pk merge
// ---------------------------------------------------------------------------
__global__ void prep_kernel(const int* __restrict__ src, const int* __restrict__ dst,
                            const int* __restrict__ pdf, const float* __restrict__ w,
                            unsigned* __restrict__ meta_t, unsigned* __restrict__ pxi,
                            float* __restrict__ wcsr,
                            int* __restrict__ pbeg, int* __restrict__ padj,
                            int N, int A, int LC)
{
    __shared__ int cnt[1024];
    __shared__ int pos[1024];
    __shared__ unsigned char gcnt[8192];
    const int g = blockIdx.x;
    src += (size_t)g * A; dst += (size_t)g * A; pdf += (size_t)g * A; w += (size_t)g * A;
    meta_t += (size_t)g * A; pxi += (size_t)g * A; wcsr += (size_t)g * A;
    pbeg += (size_t)g * (N + 1); padj += (size_t)g * N;
    const int tid = threadIdx.x;
    cnt[tid] = 0;
    __syncthreads();
    for (int a = tid; a < A; a += blockDim.x) atomicAdd(&cnt[dst[a]], 1);
    __syncthreads();
    const int deg = cnt[tid];
    pos[tid] = deg;
    __syncthreads();
    for (int off = 1; off < blockDim.x; off <<= 1) {
        int add = (tid >= off) ? pos[tid - off] : 0;
        __syncthreads();
        pos[tid] += add;
        __syncthreads();
    }
    const int r0 = pos[tid] - deg;
    const int np = deg ? (((r0 + deg - 1) >> LC) - (r0 >> LC) + 1) : 0;
    __syncthreads();
    pos[tid] = np;
    __syncthreads();
    for (int off = 1; off < blockDim.x; off <<= 1) {
        int add = (tid >= off) ? pos[tid - off] : 0;
        __syncthreads();
        pos[tid] += add;
        __syncthreads();
    }
    const int pexcl = pos[tid] - np;
    pbeg[tid] = pexcl;
    if (tid == blockDim.x - 1) pbeg[N] = pexcl + np;
    padj[tid] = pexcl - (r0 >> LC);
    cnt[tid] = r0;
    __syncthreads();
    for (int a = tid; a < A; a += blockDim.x) {
        const int d2 = dst[a];
        const int p = atomicAdd(&cnt[d2], 1);
        const int l = p >> LC;
        const int i = p & ((1 << LC) - 1);
        meta_t[(size_t)i * NTH + l] = (unsigned)src[a] | ((unsigned)d2 << 16);
        pxi[p] = (unsigned)pdf[a];
        wcsr[p] = w[a];
    }
    __syncthreads();
    const int CH = 1 << LC;
    const int ngrp = (NTH / 64) * CH;
    if (tid < ngrp) {
        unsigned char* cb = &gcnt[tid * 32];
        for (int b = 0; b < 32; ++b) cb[b] = 0;
        const int i = tid & (CH - 1);
        const int w2 = tid >> LC;
        for (int lane = 0; lane < 64; ++lane) {
            const size_t idx = (size_t)i * NTH + (w2 * 64 + lane);
            const unsigned mt = meta_t[idx];
            const unsigned sv = mt & 0xffffu;
            const unsigned alt = sv ^ ((sv >> 5) & 31u);
            const int b0 = (int)(sv & 31u), b1 = (int)(alt & 31u);
            unsigned gx;
            if (cb[b1] < cb[b0]) { cb[b1]++; gx = (unsigned)N + alt; }
            else                 { cb[b0]++; gx = sv; }
            meta_t[idx] = (mt & 0xffff0000u) | gx;
        }
    }
}

// ---------------------------------------------------------------------------
// den prep (round-5 verified logic, BP=17, weight folded out): CSR sort by
// dst; wave partition at STATE boundaries (16 waves, load <= 1063 < 1088);
// fixed BP-arc padded chunks per thread; flags for the shuffle merge:
//   segm (interior seg-end bits, tail excluded), fic, pc (<=3), cl
// plus tstate, deg0 bitmask, stride-20 padded pxi/wcsr streams, and
// two-choice bank-balanced dual-copy gather indices baked into meta.
// ---------------------------------------------------------------------------
__global__ __launch_bounds__(1024) void prep_den_kernel(
    const int* __restrict__ src, const int* __restrict__ dst,
    const int* __restrict__ pdf, const float* __restrict__ w,
    unsigned* __restrict__ meta_t, unsigned* __restrict__ pxi,
    float* __restrict__ wcsr, unsigned* __restrict__ flg,
    unsigned* __restrict__ tst, unsigned* __restrict__ deg0m)
{
    __shared__ int cnt[1024];
    __shared__ int pos[1024];
    __shared__ int rp[1025];
    __shared__ int wb[17];
    __shared__ unsigned char gcnt[16 * BP * 32];   // 8704
    const int tid = threadIdx.x;
    cnt[tid] = 0;
    __syncthreads();
    for (int a = tid; a < AD; a += 1024) atomicAdd(&cnt[dst[a]], 1);
    __syncthreads();
    const int deg = cnt[tid];
    pos[tid] = deg;
    __syncthreads();
    for (int off = 1; off < 1024; off <<= 1) {
        int add = (tid >= off) ? pos[tid - off] : 0;
        __syncthreads();
        pos[tid] += add;
        __syncthreads();
    }
    rp[tid + 1] = pos[tid];
    if (tid == 0) rp[0] = 0;
    __syncthreads();
    if (tid < 32) {
        unsigned mw = 0;
        for (int b = 0; b < 32; ++b)
            if (rp[tid * 32 + b + 1] == rp[tid * 32 + b]) mw |= (1u << b);
        deg0m[tid] = mw;
    }
    if (tid == 0) {   // wave partition at state boundaries
        int j = 0;
        wb[0] = 0;
        for (int wv = 0; wv < 16; ++wv) {
            if (wv == 15) { j = 1024; }
            else {
                const int rem = AD - rp[j];
                const int target = (rem + (15 - wv)) / (16 - wv);
                int acc = 0;
                while (j < 1024 && acc < target) { acc += rp[j + 1] - rp[j]; ++j; }
            }
            wb[wv + 1] = rp[j];
        }
    }
    __syncthreads();
    // pad pre-fill: meta (17408), pxi/wcsr stride-20 streams (20480)
    for (int p = tid; p < ADP; p += 1024) meta_t[p] = 0xFFFFFFFFu;
    for (int p = tid; p < 20480; p += 1024) { pxi[p] = 0u; wcsr[p] = -1e38f; }
    cnt[tid] = rp[tid];   // scatter cursors
    __syncthreads();
    for (int a = tid; a < AD; a += 1024) {
        const int d2 = dst[a];
        const int p = atomicAdd(&cnt[d2], 1);
        int wv = 0;
        while (p >= wb[wv + 1]) ++wv;
        const int rel = p - wb[wv];          // wave load <= 1088 -> rel/BP <= 63
        const int l = (wv << 6) + rel / BP;
        const int i = rel % BP;
        meta_t[i * NTH + l] = (unsigned)src[a] | ((unsigned)d2 << 16);
        pxi[l * 20 + i] = (unsigned)pdf[a];
        wcsr[l * 20 + i] = w[a];
    }
    __syncthreads();
    // per-thread flags
    {
        const int wv = tid >> 6;
        const int base = wb[wv], end = wb[wv + 1];
        int o0 = base + BP * (tid & 63); if (o0 > end) o0 = end;
        int o1 = base + BP * ((tid & 63) + 1); if (o1 > end) o1 = end;
        const int cl = o1 - o0;
        unsigned segm = 0;
        int prevd = -1, lastd = 0;
        for (int i = 0; i < cl; ++i) {
            const int d2 = (int)((meta_t[i * NTH + tid] >> 16) & 0x3FFu);
            if (i > 0 && d2 != prevd) segm |= (1u << (i - 1));
            prevd = d2; lastd = d2;
        }
        unsigned fic = 0;
        if (cl > 0 && o0 > base) {
            const int dprev = (int)((meta_t[(BP - 1) * NTH + (tid - 1)] >> 16) & 0x3FFu);
            const int d0x   = (int)((meta_t[0 * NTH + tid] >> 16) & 0x3FFu);
            if (dprev == d0x) fic = 1;
        }
        unsigned pcv = 0;
        if (cl > 0) {
            const int rend = rp[lastd + 1];   // state never crosses wave boundary
            if (rend > o1) { pcv = (unsigned)((rend - o1 + BP - 1) / BP); if (pcv > 3u) pcv = 3u; }
        }
        flg[tid] = segm | (fic << 19) | (pcv << 21) | ((unsigned)cl << 23);
        tst[tid] = (unsigned)lastd;
    }
    __syncthreads();
    // two-choice greedy per gather group (wave wv, slot i); pads -> index 0
    if (tid < 16 * BP) {
        unsigned char* cb = &gcnt[tid * 32];
        for (int b = 0; b < 32; ++b) cb[b] = 0;
        const int i = tid % BP;
        const int wv = tid / BP;
        for (int lane = 0; lane < 64; ++lane) {
            const int idx = i * NTH + ((wv << 6) + lane);
            const unsigned mt = meta_t[idx];
            if (mt == 0xFFFFFFFFu) { meta_t[idx] = 0u; continue; }
            const unsigned sv = mt & 0xFFFFu;
            const unsigned alt = sv ^ ((sv >> 5) & 31u);
            const int b0 = (int)(sv & 31u), b1 = (int)(alt & 31u);
            unsigned gx;
            if (cb[b1] < cb[b0]) { cb[b1]++; gx = 1024u + alt; }
            else                 { cb[b0]++; gx = sv; }
            meta_t[idx] = (mt & 0xFFFF0000u) | gx;
        }
    }
}

// ---------------------------------------------------------------------------
// W' production for one time tile: W'[inst][trel][pos] = llh[t][pdf] + w
// (weight folded in). Row staged in LDS; float4 reads/writes.
// ---------------------------------------------------------------------------
__device__ void wprep_part(int ub, int nb, int t0, int Tt, const float* __restrict__ est,
                           const unsigned* __restrict__ pxi_den,
                           const float* __restrict__ wcsr_den,
                           const unsigned* __restrict__ pxi_num,
                           const float* __restrict__ wcsr_num,
                           float* __restrict__ Wd, float* __restrict__ Wn,
                           float* row_s)
{
    const int tid = threadIdx.x;
    const int nden = 16 * Tt;
    const int total = nden + 32 * Tt;
    for (int u = ub; u < total; u += nb) {
        __syncthreads();
        const float* row; const unsigned* pxi; const float* wcs; float* out; int n4;
        if (u < nden) {
            const int inst = u / Tt, trel = u - inst * Tt;
            const int s = inst >> 3, b = inst & 7;
            row = est + ((size_t)(b * SS + s) * TT + (t0 + trel)) * CC;
            pxi = pxi_den; wcs = wcsr_den;
            out = Wd + ((size_t)inst * Tt + trel) * WSD;
            n4 = WSD >> 2;
        } else {
            const int v = u - nden;
            const int inst = v / Tt, trel = v - inst * Tt;
            const int gg = inst & 15, p = inst >> 4;
            const int s = gg >> 3, b = gg & 7;
            const int sp = p ? (1 - s) : s;
            row = est + ((size_t)(b * SS + sp) * TT + (t0 + trel)) * CC;
            pxi = pxi_num + (size_t)gg * AN; wcs = wcsr_num + (size_t)gg * AN;
            out = Wn + ((size_t)inst * Tt + trel) * AN;
            n4 = AN >> 2;
        }
        row_s[tid] = row[tid]; row_s[tid + 1024] = row[tid + 1024];
        __syncthreads();
        const uint4* p4 = (const uint4*)pxi;
        const float4* w4 = (const float4*)wcs;
        float4* o4 = (float4*)out;
        for (int k = tid; k < n4; k += 1024) {
            const uint4 pp = p4[k];
            const float4 ww = w4[k];
            o4[k] = make_float4(row_s[pp.x] + ww.x, row_s[pp.y] + ww.y,
                                row_s[pp.z] + ww.z, row_s[pp.w] + ww.w);
        }
    }
}

__global__ __launch_bounds__(1024) void wprep0_kernel(
    const float* __restrict__ est,
    const unsigned* __restrict__ pxi_den, const float* __restrict__ wcsr_den,
    const unsigned* __restrict__ pxi_num, const float* __restrict__ wcsr_num,
    float* __restrict__ Wd, float* __restrict__ Wn, int t0, int Tt)
{
    __shared__ float row_s[CC];
    wprep_part(blockIdx.x, gridDim.x, t0, Tt, est, pxi_den, wcsr_den,
               pxi_num, wcsr_num, Wd, Wn, row_s);
}

// ---------------------------------------------------------------------------
// den forward: wave-aligned BP=17 chunks, meta register-resident, dual-copy
// DOUBLE-BUFFERED alpha, two-pass segmented LSE, shuffle-merged tails,
// ONE barrier per step. W' (= w + llh) streamed, prefetched 1 step ahead.
// Reference semantics preserved (same partial class that has passed r1-r7).
// ---------------------------------------------------------------------------
__device__ void fsm_forward_den(int L, int t0, int Tt, bool first, bool last,
    const float* __restrict__ Wrow0,
    const unsigned* __restrict__ meta_g,
    const unsigned* __restrict__ flg_g, const unsigned* __restrict__ tst_g,
    const unsigned* __restrict__ deg0m,
    const float* __restrict__ initv, const float* __restrict__ finalv,
    float* __restrict__ alpha_gl, float* __restrict__ res,
    float* bufA, float* bufB, float* red)
{
    const int tid = threadIdx.x;
    unsigned meta[BP];
#pragma unroll
    for (int i = 0; i < BP; ++i) meta[i] = meta_g[i * NTH + tid];
    const unsigned fl = flg_g[tid];
    const unsigned segm = fl & 0xFFFFu;
    const unsigned fic  = (fl >> 19) & 1u;
    const unsigned pc   = (fl >> 21) & 3u;
    const int      cl   = (int)(fl >> 23);
    const bool     own  = (cl > 0) && !(fic && segm == 0u);
    const unsigned wmask = fic ? (segm & (segm - 1u)) : segm;
    const int tstate = (int)tst_g[tid];
    const int tdual  = 1024 + (tstate ^ ((tstate >> 5) & 31));
    const int sdual  = 1024 + (tid ^ ((tid >> 5) & 31));
    const unsigned d0 = (deg0m[tid >> 5] >> (tid & 31)) & 1u;
    const float c0 = NEGV + __logf(1e-30f);   // reference no-in-arc value
    const float fin = finalv[tid];

    const float a0 = first ? initv[tid] : alpha_gl[tid];
    bufA[tid] = a0;
    bufA[sdual] = a0;
    int tb = L - t0; if (tb > Tt) tb = Tt; if (tb < 0) tb = 0;
    float wc[BP];
    if (tb > 0) {
        const float* p = Wrow0 + (size_t)tid * 20;
#pragma unroll
        for (int q = 0; q < 4; ++q) {
            const float4 v = ((const float4*)p)[q];
            wc[4*q] = v.x; wc[4*q+1] = v.y; wc[4*q+2] = v.z; wc[4*q+3] = v.w;
        }
        wc[16] = p[16];
    }
    __syncthreads();

    float* cur = bufA; float* nxt = bufB;
    for (int trel = 0; trel < tb; ++trel) {
        const bool pre = (trel + 1 < tb);
        float wn[BP];
        if (pre) {   // prefetch next step's W'; hides under this step
            const float* p = Wrow0 + (size_t)(trel + 1) * WSD + (size_t)tid * 20;
#pragma unroll
            for (int q = 0; q < 4; ++q) {
                const float4 v = ((const float4*)p)[q];
                wn[4*q] = v.x; wn[4*q+1] = v.y; wn[4*q+2] = v.z; wn[4*q+3] = v.w;
            }
            wn[16] = p[16];
        }
        // batch gathers; sc consumes wc (pads: sc ~ -1e38)
        float sc[BP];
#pragma unroll
        for (int i = 0; i < BP; ++i)
            sc[i] = cur[meta[i] & 0xFFFFu] + wc[i];
        // forward running max with reset at interior segment ends
        float pm[BP];
        {
            float m = -INFINITY;
#pragma unroll
            for (int i = 0; i < BP; ++i) {
                m = fmaxf(m, sc[i]);
                pm[i] = m;
                if (segm & (1u << i)) m = -INFINITY;
            }
        }
        const float tm0 = pm[BP - 1];        // tail segment max
        // backward: per-arc segment max
        float sm[BP];
        sm[BP - 1] = tm0;
#pragma unroll
        for (int i = BP - 2; i >= 0; --i)
            sm[i] = (segm & (1u << i)) ? pm[i] : sm[i + 1];
        // ordered sums; finalize owned interior segments; capture head + tail
        float ssn = 0.f, hm = 0.f, hs = 0.f;
        bool hcap = false;
#pragma unroll
        for (int i = 0; i < BP; ++i) {
            ssn += __expf(sc[i] - sm[i]);    // pads contribute 0 in real segs
            if (segm & (1u << i)) {
                if (!hcap) { hm = sm[i]; hs = ssn; hcap = true; }
                if (wmask & (1u << i)) {     // fully-owned: finalize now
                    const float mc  = fmaxf(sm[i], NEGV);
                    const float scs = ssn * __expf(sm[i] - mc);
                    const float v2  = mc + __logf(fmaxf(scs, 1e-30f));
                    const int dj = (int)((meta[i] >> 16) & 0x3FFu);
                    nxt[dj] = v2;
                    nxt[1024 + (dj ^ ((dj >> 5) & 31))] = v2;
                }
                ssn = 0.f;
            }
        }
        const float ts0 = ssn;
        if (!hcap) { hm = tm0; hs = ts0; }   // solo chunk: head == tail
        // pull continuation head partials from lanes +1..+3 (same wave by prep)
        const float h1m = __shfl_down(hm, 1), h1s = __shfl_down(hs, 1);
        const float h2m = __shfl_down(hm, 2), h2s = __shfl_down(hs, 2);
        const float h3m = __shfl_down(hm, 3), h3s = __shfl_down(hs, 3);
        float tm = tm0, ts = ts0;
        if (pc >= 1u) LSE_MERGE(tm, ts, h1m, h1s);
        if (pc >= 2u) LSE_MERGE(tm, ts, h2m, h2s);
        if (pc >= 3u) LSE_MERGE(tm, ts, h3m, h3s);
        if (own) {
            const float mc  = fmaxf(tm, NEGV);
            const float scs = ts * __expf(tm - mc);
            const float v2  = mc + __logf(fmaxf(scs, 1e-30f));
            nxt[tstate] = v2;
            nxt[tdual]  = v2;
        }
        if (d0) { nxt[tid] = c0; nxt[sdual] = c0; }
        __syncthreads();                  // the ONLY barrier per step
        float* t2 = cur; cur = nxt; nxt = t2;
        if (pre) {
#pragma unroll
            for (int i = 0; i < BP; ++i) wc[i] = wn[i];
        }
    }

    if (last) {
        const float v = cur[tid] + fin;
        red[tid] = v;
        __syncthreads();
        for (int off = 512; off > 0; off >>= 1) {
            if (tid < off) red[tid] = fmaxf(red[tid], red[tid + off]);
            __syncthreads();
        }
        const float M = red[0];
        __syncthreads();
        red[tid] = __expf(v - M);
        __syncthreads();
        for (int off = 512; off > 0; off >>= 1) {
            if (tid < off) red[tid] += red[tid + off];
            __syncthreads();
        }
        if (tid == 0) *res = M + __logf(red[0]);
    } else {
        alpha_gl[tid] = cur[tid];
    }
}

// ---------------------------------------------------------------------------
// num forward (r7 path minus wreg): CH=2 chunks, two-pass per-chunk LSE,
// pk partial merge, two barriers. Not the critical path.
// ---------------------------------------------------------------------------
__device__ void fsm_forward_num(int L, int t0, int Tt, bool first, bool last,
    const float* __restrict__ Wrow0,
    const unsigned* __restrict__ meta_g,
    const int* __restrict__ pbeg_g, const int* __restrict__ padj_g,
    const float* __restrict__ initv, const float* __restrict__ finalv,
    float* __restrict__ alpha_gl, float* __restrict__ res,
    float* alpha_s, float2* pk)
{
    const int tid = threadIdx.x;
    unsigned meta[2];
    meta[0] = meta_g[tid];
    meta[1] = meta_g[NTH + tid];
    const bool sameseg = ((meta[0] >> 16) == (meta[1] >> 16));
    const int slot0 = padj_g[meta[0] >> 16] + tid;
    const bool st = tid < NN;
    int pb0 = 0, pb1 = 0; float fin = 0.f;
    if (st) {
        const float a0 = first ? initv[tid] : alpha_gl[tid];
        alpha_s[tid] = a0;
        alpha_s[NN + (tid ^ ((tid >> 5) & 31))] = a0;
        pb0 = pbeg_g[tid]; pb1 = pbeg_g[tid + 1];
        fin = finalv[tid];
    }
    int tb = L - t0; if (tb > Tt) tb = Tt; if (tb < 0) tb = 0;
    float wc0 = 0.f, wc1 = 0.f;
    if (tb > 0) {
        const float2 v = *(const float2*)(Wrow0 + (size_t)tid * 2);
        wc0 = v.x; wc1 = v.y;
    }
    __syncthreads();

    for (int trel = 0; trel < tb; ++trel) {
        const bool pre = (trel + 1 < tb);
        float wn0 = 0.f, wn1 = 0.f;
        if (pre) {
            const float2 v = *(const float2*)(Wrow0 + (size_t)(trel + 1) * AN + (size_t)tid * 2);
            wn0 = v.x; wn1 = v.y;
        }
        const float s0 = alpha_s[meta[0] & 0xffffu] + wc0;
        const float s1 = alpha_s[meta[1] & 0xffffu] + wc1;
        if (sameseg) {
            const float m = fmaxf(s0, s1);
            pk[slot0] = make_float2(m, __expf(s0 - m) + __expf(s1 - m));
        } else {
            pk[slot0]     = make_float2(s0, 1.f);
            pk[slot0 + 1] = make_float2(s1, 1.f);
        }
        __syncthreads();
        if (st) {
            float v2;
            const int cnt2 = pb1 - pb0;
            if (cnt2 > 0) {
                const float2 P0 = pk[pb0];
                float mm = P0.x, s2 = P0.y;
                for (int q2 = pb0 + 1; q2 < pb1; ++q2) {
                    const float2 Pq = pk[q2];
                    LSE_MERGE(mm, s2, Pq.x, Pq.y);
                }
                const float mc  = fmaxf(mm, NEGV);
                const float scs = s2 * __expf(mm - mc);
                v2 = mc + __logf(fmaxf(scs, 1e-30f));
            } else {
                v2 = NEGV + __logf(1e-30f);
            }
            alpha_s[tid] = v2;
            alpha_s[NN + (tid ^ ((tid >> 5) & 31))] = v2;
        }
        __syncthreads();
        if (pre) { wc0 = wn0; wc1 = wn1; }
    }

    if (last) {
        const float v = st ? (alpha_s[tid] + fin) : -INFINITY;
        float* red = (float*)pk;
        red[tid] = v;
        __syncthreads();
        for (int off = 512; off > 0; off >>= 1) {
            if (tid < off) red[tid] = fmaxf(red[tid], red[tid + off]);
            __syncthreads();
        }
        const float M = red[0];
        __syncthreads();
        red[tid] = __expf(v - M);
        __syncthreads();
        for (int off = 512; off > 0; off >>= 1) {
            if (tid < off) red[tid] += red[tid + off];
            __syncthreads();
        }
        if (tid == 0) *res = M + __logf(red[0]);
    } else if (st) {
        alpha_gl[tid] = alpha_s[tid];
    }
}

// ---------------------------------------------------------------------------
// fused (grid NWG=256): 0..15 den fwd, 16..47 num fwd, 48..255 wprep tile k+1.
// __launch_bounds__(1024, 4): 4 waves/SIMD -> VGPR cap 128 so den's ~93 live
// values stay in registers (round-5 failed at the default 64-reg choice).
// ---------------------------------------------------------------------------
__global__ __launch_bounds__(1024, 4) void fused_kernel(
    const int* __restrict__ seqlen,
    const float* __restrict__ Wd, const float* __restrict__ Wn,
    const unsigned* __restrict__ den_meta,
    const unsigned* __restrict__ den_flg, const unsigned* __restrict__ den_tst,
    const unsigned* __restrict__ den_deg0,
    const float* __restrict__ den_init, const float* __restrict__ den_final,
    const unsigned* __restrict__ num_meta,
    const int* __restrict__ num_pbeg, const int* __restrict__ num_padj,
    const float* __restrict__ num_init, const float* __restrict__ num_final,
    float* __restrict__ alpha_g, float* __restrict__ res,
    int t0, int Tt, int last,
    const float* __restrict__ est,
    const unsigned* __restrict__ pxi_den, const float* __restrict__ wcsr_den,
    const unsigned* __restrict__ pxi_num, const float* __restrict__ wcsr_num,
    float* __restrict__ Wd_next, float* __restrict__ Wn_next)
{
    __shared__ float bufA[2048];
    __shared__ float bufB[2048];
    __shared__ float2 pk[2048];
    __shared__ float row_s[CC];
    const int bid = blockIdx.x;
    const bool first = (t0 == 0);
    if (bid >= 48) {
        if (!last)
            wprep_part(bid - 48, NWG - 48, t0 + Tt, Tt, est,
                       pxi_den, wcsr_den, pxi_num, wcsr_num,
                       Wd_next, Wn_next, row_s);
        return;
    }
    if (bid < 16) {
        const int s = bid >> 3, b = bid & 7;
        const int L = seqlen[b * SS + s];
        fsm_forward_den(L, t0, Tt, first, last != 0,
                        Wd + (size_t)bid * Tt * WSD,
                        den_meta, den_flg, den_tst, den_deg0,
                        den_init, den_final,
                        alpha_g + (size_t)bid * 1024, &res[bid],
                        bufA, bufB, (float*)pk);
    } else {
        const int q = bid - 16;
        const int p = q >> 4, g = q & 15;
        const int s = g >> 3, b = g & 7;
        const int sp = p ? (1 - s) : s;
        const int L = seqlen[b * SS + sp];
        fsm_forward_num(L, t0, Tt, first, last != 0,
                        Wn + (size_t)q * Tt * AN,
                        num_meta + (size_t)g * AN,
                        num_pbeg + (size_t)g * (NN + 1), num_padj + (size_t)g * NN,
                        num_init + (size_t)g * NN, num_final + (size_t)g * NN,
                        alpha_g + (size_t)bid * 1024, &res[16 + q], bufA, pk);
    }
}

// res layout: [0..15] den (s*8+b), [16..31] num perm0, [32..47] num perm1
__global__ void finalize_kernel(const float* __restrict__ res, float* __restrict__ out)
{
    if (threadIdx.x == 0 && blockIdx.x == 0) {
        float loss = 0.f;
        for (int b = 0; b < BB; ++b) {
            const float den = res[b] + res[8 + b];
            const float n0  = res[16 + b] + res[16 + 8 + b];
            const float n1  = res[32 + b] + res[32 + 8 + b];
            const float nm  = fminf(n0, n1);
            loss += -(nm - den);
        }
        out[0] = loss;
    }
}

extern "C" void kernel_launch(void* const* d_in, const int* in_sizes, int n_in,
                              void* d_out, int out_size, void* d_ws, size_t ws_size,
                              hipStream_t stream)
{
    const float* est       = (const float*)d_in[0];
    const int*   seqlen    = (const int*)  d_in[1];
    const int*   den_src   = (const int*)  d_in[2];
    const int*   den_dst   = (const int*)  d_in[3];
    const int*   den_pdf   = (const int*)  d_in[4];
    const float* den_w     = (const float*)d_in[5];
    const float* den_init  = (const float*)d_in[6];
    const float* den_final = (const float*)d_in[7];
    const int*   num_src   = (const int*)  d_in[8];
    const int*   num_dst   = (const int*)  d_in[9];
    const int*   num_pdf   = (const int*)  d_in[10];
    const float* num_w     = (const float*)d_in[11];
    const float* num_init  = (const float*)d_in[12];
    const float* num_final = (const float*)d_in[13];

    char* ws = (char*)d_ws;
    unsigned* den_meta = (unsigned*)(ws + 0);        //  69632 -> 69632 (pad 69888)
    unsigned* den_pxi  = (unsigned*)(ws + 69888);    //  81920 -> 151808
    float*    den_wcsr = (float*)   (ws + 151808);   //  81920 -> 233728
    unsigned* num_meta = (unsigned*)(ws + 233728);   // 131072 -> 364800
    unsigned* num_pxi  = (unsigned*)(ws + 364800);   // 131072 -> 495872
    float*    num_wcsr = (float*)   (ws + 495872);   // 131072 -> 626944
    int*      num_pbeg = (int*)     (ws + 626944);   //  16448 -> 643392 (pad 643456)
    int*      num_padj = (int*)     (ws + 643456);   //  16384 -> 659840
    unsigned* den_flg  = (unsigned*)(ws + 659840);   //   4096 -> 663936
    unsigned* den_tst  = (unsigned*)(ws + 663936);   //   4096 -> 668032
    unsigned* den_deg0 = (unsigned*)(ws + 668032);   //    128 -> 668160
    float*    alpha_g  = (float*)   (ws + 668160);   // 196608 -> 864768
    float*    res      = (float*)   (ws + 864768);   //    192 -> 864960 (pad 865024)
    const size_t fixed = 865024;

    // W' double buffer: per trel (16*WSD + 32*AN)*4 = 1572864 B (r5-verified fit)
    int Tt = 64;
    while (Tt > 4 && fixed + 2ull * (size_t)Tt * 1572864ull > ws_size) Tt >>= 1;
    const size_t wbuf_f = (size_t)Tt * (16 * WSD + 32 * AN);
    float* Wd0 = (float*)(ws + fixed);
    float* Wn0 = Wd0 + (size_t)16 * Tt * WSD;
    float* Wd1 = Wd0 + wbuf_f;
    float* Wn1 = Wd1 + (size_t)16 * Tt * WSD;

    prep_den_kernel<<<1, 1024, 0, stream>>>(den_src, den_dst, den_pdf, den_w,
                                            den_meta, den_pxi, den_wcsr,
                                            den_flg, den_tst, den_deg0);
    prep_kernel<<<16, 256, 0, stream>>>(num_src, num_dst, num_pdf, num_w,
                                        num_meta, num_pxi, num_wcsr,
                                        num_pbeg, num_padj, NN, AN, 1);

    wprep0_kernel<<<256, 1024, 0, stream>>>(est, den_pxi, den_wcsr,
                                            num_pxi, num_wcsr, Wd0, Wn0, 0, Tt);

    const int nt = TT / Tt;
    for (int k = 0; k < nt; ++k) {
        float* WdC = (k & 1) ? Wd1 : Wd0;
        float* WnC = (k & 1) ? Wn1 : Wn0;
        float* WdN = (k & 1) ? Wd0 : Wd1;
        float* WnN = (k & 1) ? Wn0 : Wn1;
        fused_kernel<<<NWG, 1024, 0, stream>>>(seqlen, WdC, WnC,
                                               den_meta, den_flg, den_tst, den_deg0,
                                               den_init, den_final,
                                               num_meta, num_pbeg, num_padj,
                                               num_init, num_final,
                                               alpha_g, res, k * Tt, Tt,
                                               (k == nt - 1) ? 1 : 0,
                                               est, den_pxi, den_wcsr,
                                               num_pxi, num_wcsr, WdN, WnN);
    }

    finalize_kernel<<<1, 64, 0, stream>>>(res, (float*)d_out);
}

// Round 9
// 2164.707 us; speedup vs baseline: 1.0181x; 1.0181x over previous
//
#include <hip/hip_runtime.h>
#include <cstdint>
#include <cstddef>

#define BB 8
#define SS 2
#define TT 512
#define CC 2048
#define ND 1024
#define AD 16384
#define NN 256
#define AN 2048
#define NEGV -1e30f
#define NTH 1024    // fwd block threads
#define NWG 256     // fused grid: 16 den + 32 num + 208 wprep workers

// guarded online-LSE merge (same rounding class as all passing rounds)
#define LSE_MERGE(mm, s2, m2, sp) do { \
    const float _d = (m2) - (mm); const float _e = __expf(-fabsf(_d)); \
    if (_d > 0.f) { s2 = s2 * _e + (sp); mm = (m2); } else { s2 += (sp) * _e; } } while (0)

// ---------------------------------------------------------------------------
// num prep (r8, passed): counting sort by dst into chunk-transposed SoA
//   meta = gidx | dst<<16 (two-choice bank-balanced dual-copy gather index)
//   pxi/wcsr: CSR-order pdf and weight for the W' precompute
//   pbeg/padj: partial-slot tables for the pk merge
// ---------------------------------------------------------------------------
__global__ void prep_kernel(const int* __restrict__ src, const int* __restrict__ dst,
                            const int* __restrict__ pdf, const float* __restrict__ w,
                            unsigned* __restrict__ meta_t, unsigned* __restrict__ pxi,
                            float* __restrict__ wcsr,
                            int* __restrict__ pbeg, int* __restrict__ padj,
                            int N, int A, int LC)
{
    __shared__ int cnt[1024];
    __shared__ int pos[1024];
    __shared__ unsigned char gcnt[8192];
    const int g = blockIdx.x;
    src += (size_t)g * A; dst += (size_t)g * A; pdf += (size_t)g * A; w += (size_t)g * A;
    meta_t += (size_t)g * A; pxi += (size_t)g * A; wcsr += (size_t)g * A;
    pbeg += (size_t)g * (N + 1); padj += (size_t)g * N;
    const int tid = threadIdx.x;
    cnt[tid] = 0;
    __syncthreads();
    for (int a = tid; a < A; a += blockDim.x) atomicAdd(&cnt[dst[a]], 1);
    __syncthreads();
    const int deg = cnt[tid];
    pos[tid] = deg;
    __syncthreads();
    for (int off = 1; off < blockDim.x; off <<= 1) {
        int add = (tid >= off) ? pos[tid - off] : 0;
        __syncthreads();
        pos[tid] += add;
        __syncthreads();
    }
    const int r0 = pos[tid] - deg;
    const int np = deg ? (((r0 + deg - 1) >> LC) - (r0 >> LC) + 1) : 0;
    __syncthreads();
    pos[tid] = np;
    __syncthreads();
    for (int off = 1; off < blockDim.x; off <<= 1) {
        int add = (tid >= off) ? pos[tid - off] : 0;
        __syncthreads();
        pos[tid] += add;
        __syncthreads();
    }
    const int pexcl = pos[tid] - np;
    pbeg[tid] = pexcl;
    if (tid == blockDim.x - 1) pbeg[N] = pexcl + np;
    padj[tid] = pexcl - (r0 >> LC);
    cnt[tid] = r0;
    __syncthreads();
    for (int a = tid; a < A; a += blockDim.x) {
        const int d2 = dst[a];
        const int p = atomicAdd(&cnt[d2], 1);
        const int l = p >> LC;
        const int i = p & ((1 << LC) - 1);
        meta_t[(size_t)i * NTH + l] = (unsigned)src[a] | ((unsigned)d2 << 16);
        pxi[p] = (unsigned)pdf[a];
        wcsr[p] = w[a];
    }
    __syncthreads();
    const int CH = 1 << LC;
    const int ngrp = (NTH / 64) * CH;
    if (tid < ngrp) {
        unsigned char* cb = &gcnt[tid * 32];
        for (int b = 0; b < 32; ++b) cb[b] = 0;
        const int i = tid & (CH - 1);
        const int w2 = tid >> LC;
        for (int lane = 0; lane < 64; ++lane) {
            const size_t idx = (size_t)i * NTH + (w2 * 64 + lane);
            const unsigned mt = meta_t[idx];
            const unsigned sv = mt & 0xffffu;
            const unsigned alt = sv ^ ((sv >> 5) & 31u);
            const int b0 = (int)(sv & 31u), b1 = (int)(alt & 31u);
            unsigned gx;
            if (cb[b1] < cb[b0]) { cb[b1]++; gx = (unsigned)N + alt; }
            else                 { cb[b0]++; gx = sv; }
            meta_t[idx] = (mt & 0xffff0000u) | gx;
        }
    }
}

// ---------------------------------------------------------------------------
// den prep (new): CSR sort by dst into UNALIGNED CH=16 chunks (AD = 16*1024
// exactly -> no padding, every thread has 16 real arcs). Per-thread flags for
// the shuffle merge (r5-verified logic): segm (interior seg-end bits, tail
// excluded), fic (first arc continues prev thread's tail), pc (continuation
// threads, <=3). Plus tstate, deg0 bitmask, CSR-order pdf/weight streams,
// and two-choice bank-balanced dual-copy gather indices baked into meta.
// ---------------------------------------------------------------------------
__global__ __launch_bounds__(1024) void prep_den_kernel(
    const int* __restrict__ src, const int* __restrict__ dst,
    const int* __restrict__ pdf, const float* __restrict__ w,
    unsigned* __restrict__ meta_t, unsigned* __restrict__ pxi,
    float* __restrict__ wcsr, unsigned* __restrict__ flg,
    unsigned* __restrict__ tst, unsigned* __restrict__ deg0m)
{
    __shared__ int cnt[1024];
    __shared__ int pos[1024];
    __shared__ int rp[1025];
    __shared__ unsigned char gcnt[8192];
    const int tid = threadIdx.x;
    cnt[tid] = 0;
    __syncthreads();
    for (int a = tid; a < AD; a += 1024) atomicAdd(&cnt[dst[a]], 1);
    __syncthreads();
    const int deg = cnt[tid];
    pos[tid] = deg;
    __syncthreads();
    for (int off = 1; off < 1024; off <<= 1) {
        int add = (tid >= off) ? pos[tid - off] : 0;
        __syncthreads();
        pos[tid] += add;
        __syncthreads();
    }
    rp[tid + 1] = pos[tid];
    if (tid == 0) rp[0] = 0;
    __syncthreads();
    if (tid < 32) {
        unsigned mw = 0;
        for (int b = 0; b < 32; ++b)
            if (rp[tid * 32 + b + 1] == rp[tid * 32 + b]) mw |= (1u << b);
        deg0m[tid] = mw;
    }
    cnt[tid] = rp[tid];   // scatter cursors
    __syncthreads();
    for (int a = tid; a < AD; a += 1024) {
        const int d2 = dst[a];
        const int p = atomicAdd(&cnt[d2], 1);
        meta_t[(p & 15) * NTH + (p >> 4)] = (unsigned)src[a] | ((unsigned)d2 << 16);
        pxi[p] = (unsigned)pdf[a];
        wcsr[p] = w[a];
    }
    __syncthreads();
    // per-thread flags (thread l = tid owns arcs [16l, 16l+16))
    {
        unsigned segm = 0;
        int prevd = -1, lastd = 0;
        for (int i = 0; i < 16; ++i) {
            const int d2 = (int)((meta_t[i * NTH + tid] >> 16) & 0x3FFu);
            if (i > 0 && d2 != prevd) segm |= (1u << (i - 1));
            prevd = d2; lastd = d2;
        }
        unsigned fic = 0;
        if (tid > 0) {
            const int dprev = (int)((meta_t[15 * NTH + (tid - 1)] >> 16) & 0x3FFu);
            const int d00   = (int)((meta_t[tid] >> 16) & 0x3FFu);
            if (dprev == d00) fic = 1;
        }
        const int o1 = 16 * (tid + 1);
        const int rend = rp[lastd + 1];
        unsigned pcv = 0;
        if (rend > o1) { pcv = (unsigned)((rend - o1 + 15) >> 4); if (pcv > 3u) pcv = 3u; }
        flg[tid] = segm | (fic << 19) | (pcv << 21);
        tst[tid] = (unsigned)lastd;
    }
    __syncthreads();
    // two-choice greedy per gather group (wave w2, slot i): 256 groups
    if (tid < 256) {
        unsigned char* cb = &gcnt[tid * 32];
        for (int b = 0; b < 32; ++b) cb[b] = 0;
        const int i = tid & 15;
        const int w2 = tid >> 4;
        for (int lane = 0; lane < 64; ++lane) {
            const int idx = i * NTH + (w2 * 64 + lane);
            const unsigned mt = meta_t[idx];
            const unsigned sv = mt & 0xFFFFu;
            const unsigned alt = sv ^ ((sv >> 5) & 31u);
            const int b0 = (int)(sv & 31u), b1 = (int)(alt & 31u);
            unsigned gx;
            if (cb[b1] < cb[b0]) { cb[b1]++; gx = 1024u + alt; }
            else                 { cb[b0]++; gx = sv; }
            meta_t[idx] = (mt & 0xFFFF0000u) | gx;
        }
    }
}

// ---------------------------------------------------------------------------
// W' production for one time tile: W'[inst][trel][pos] = llh[t][pdf] + w
// (weight folded in, r8 verified). Den stream is plain AD (no padding).
// ---------------------------------------------------------------------------
__device__ void wprep_part(int ub, int nb, int t0, int Tt, const float* __restrict__ est,
                           const unsigned* __restrict__ pxi_den,
                           const float* __restrict__ wcsr_den,
                           const unsigned* __restrict__ pxi_num,
                           const float* __restrict__ wcsr_num,
                           float* __restrict__ Wd, float* __restrict__ Wn,
                           float* row_s)
{
    const int tid = threadIdx.x;
    const int nden = 16 * Tt;
    const int total = nden + 32 * Tt;
    for (int u = ub; u < total; u += nb) {
        __syncthreads();
        const float* row; const unsigned* pxi; const float* wcs; float* out; int n4;
        if (u < nden) {
            const int inst = u / Tt, trel = u - inst * Tt;
            const int s = inst >> 3, b = inst & 7;
            row = est + ((size_t)(b * SS + s) * TT + (t0 + trel)) * CC;
            pxi = pxi_den; wcs = wcsr_den;
            out = Wd + ((size_t)inst * Tt + trel) * AD;
            n4 = AD >> 2;
        } else {
            const int v = u - nden;
            const int inst = v / Tt, trel = v - inst * Tt;
            const int gg = inst & 15, p = inst >> 4;
            const int s = gg >> 3, b = gg & 7;
            const int sp = p ? (1 - s) : s;
            row = est + ((size_t)(b * SS + sp) * TT + (t0 + trel)) * CC;
            pxi = pxi_num + (size_t)gg * AN; wcs = wcsr_num + (size_t)gg * AN;
            out = Wn + ((size_t)inst * Tt + trel) * AN;
            n4 = AN >> 2;
        }
        row_s[tid] = row[tid]; row_s[tid + 1024] = row[tid + 1024];
        __syncthreads();
        const uint4* p4 = (const uint4*)pxi;
        const float4* w4 = (const float4*)wcs;
        float4* o4 = (float4*)out;
        for (int k = tid; k < n4; k += 1024) {
            const uint4 pp = p4[k];
            const float4 ww = w4[k];
            o4[k] = make_float4(row_s[pp.x] + ww.x, row_s[pp.y] + ww.y,
                                row_s[pp.z] + ww.z, row_s[pp.w] + ww.w);
        }
    }
}

__global__ __launch_bounds__(1024) void wprep0_kernel(
    const float* __restrict__ est,
    const unsigned* __restrict__ pxi_den, const float* __restrict__ wcsr_den,
    const unsigned* __restrict__ pxi_num, const float* __restrict__ wcsr_num,
    float* __restrict__ Wd, float* __restrict__ Wn, int t0, int Tt)
{
    __shared__ float row_s[CC];
    wprep_part(blockIdx.x, gridDim.x, t0, Tt, est, pxi_den, wcsr_den,
               pxi_num, wcsr_num, Wd, Wn, row_s);
}

// ---------------------------------------------------------------------------
// den forward: unaligned CH=16 chunks, ONLINE single-pass LSE (r4 math),
// dual-copy double-buffered alpha, shuffle-merged tails (r5 logic, pc<=3),
// cross-wave continuation heads via LDS + per-wave step flag (spin, safe:
// all 16 waves of the block are co-resident; republish only after the
// end-of-step barrier). ONE barrier per step. Register budget ~76 live.
// ---------------------------------------------------------------------------
__device__ void fsm_forward_den(int L, int t0, int Tt, bool first, bool last,
    const float* __restrict__ Wrow0,
    const unsigned* __restrict__ meta_g,
    const unsigned* __restrict__ flg_g, const unsigned* __restrict__ tst_g,
    const unsigned* __restrict__ deg0m,
    const float* __restrict__ initv, const float* __restrict__ finalv,
    float* __restrict__ alpha_gl, float* __restrict__ res,
    float* bufA, float* bufB,
    volatile float* hsm, volatile float* hss, volatile int* hflag)
{
    const int tid = threadIdx.x;
    const int lane = tid & 63, wv = tid >> 6;
    unsigned meta[16];
#pragma unroll
    for (int i = 0; i < 16; ++i) meta[i] = meta_g[i * NTH + tid];
    const unsigned fl = flg_g[tid];
    const unsigned segm = fl & 0x7FFFu;
    const unsigned fic  = (fl >> 19) & 1u;
    const int      pc   = (int)((fl >> 21) & 7u);
    const bool own = !(fic && segm == 0u);
    const unsigned wmask = fic ? (segm & (segm - 1u)) : segm;
    const int tstate = (int)tst_g[tid];
    const int tdual  = 1024 + (tstate ^ ((tstate >> 5) & 31));
    const int sdual  = 1024 + (tid ^ ((tid >> 5) & 31));
    const unsigned d0 = (deg0m[tid >> 5] >> (tid & 31)) & 1u;
    const float c0 = NEGV + __logf(1e-30f);   // reference no-in-arc value
    const float fin = finalv[tid];

    const float a0 = first ? initv[tid] : alpha_gl[tid];
    bufA[tid] = a0;
    bufA[sdual] = a0;
    if (tid < 16) hflag[tid] = -1;
    int tb = L - t0; if (tb > Tt) tb = Tt; if (tb < 0) tb = 0;
    float wc[16];
    if (tb > 0) {
        const float4* p = (const float4*)(Wrow0 + (size_t)tid * 16);
#pragma unroll
        for (int q = 0; q < 4; ++q) {
            const float4 v = p[q];
            wc[4*q] = v.x; wc[4*q+1] = v.y; wc[4*q+2] = v.z; wc[4*q+3] = v.w;
        }
    }
    __syncthreads();

    float* cur = bufA; float* nxt = bufB;
    for (int trel = 0; trel < tb; ++trel) {
        const bool pre = (trel + 1 < tb);
        float wn[16];
        if (pre) {   // prefetch next step's W'; hides under this step
            const float4* p = (const float4*)(Wrow0 + (size_t)(trel + 1) * AD + (size_t)tid * 16);
#pragma unroll
            for (int q = 0; q < 4; ++q) {
                const float4 v = p[q];
                wn[4*q] = v.x; wn[4*q+1] = v.y; wn[4*q+2] = v.z; wn[4*q+3] = v.w;
            }
        }
        // phase 1: online segmented LSE (r4 op sequence), interior finalize
        float m = -INFINITY, ss = 0.f, hm = 0.f, hs = 0.f;
        bool hcap = false;
#pragma unroll
        for (int i0 = 0; i0 < 16; i0 += 8) {
            float av[8];
#pragma unroll
            for (int k2 = 0; k2 < 8; ++k2)
                av[k2] = cur[meta[i0 + k2] & 0xFFFFu];
#pragma unroll
            for (int k2 = 0; k2 < 8; ++k2) {
                const int i = i0 + k2;
                const float sc = av[k2] + wc[i];
                const float d = sc - m;                 // first arc of seg: +inf
                const float e = __expf(-fabsf(d));      // exp(-inf) = 0
                if (d > 0.f) { ss = ss * e + 1.f; m = sc; }
                else         { ss += e; }
                if (segm & (1u << i)) {                 // interior segment end
                    if (!hcap) { hm = m; hs = ss; hcap = true; }
                    if (wmask & (1u << i)) {            // fully-owned: finalize
                        const float mc  = fmaxf(m, NEGV);
                        const float scs = ss * __expf(m - mc);
                        const float v2  = mc + __logf(fmaxf(scs, 1e-30f));
                        const int dj = (int)((meta[i] >> 16) & 0x3FFu);
                        nxt[dj] = v2;
                        nxt[1024 + (dj ^ ((dj >> 5) & 31))] = v2;
                    }
                    m = -INFINITY; ss = 0.f;
                }
            }
        }
        if (!hcap) { hm = m; hs = ss; }   // solo chunk: head == tail
        // publish heads (lanes 0..2) for cross-wave continuation owners
        if (lane < 3) { hsm[wv * 4 + lane] = hm; hss[wv * 4 + lane] = hs; }
        __threadfence_block();
        if (lane == 0) hflag[wv] = trel;
        // in-wave head pulls (unconditional: full-wave shuffles)
        const float s1m = __shfl_down(hm, 1), s1s = __shfl_down(hs, 1);
        const float s2m = __shfl_down(hm, 2), s2s = __shfl_down(hs, 2);
        const float s3m = __shfl_down(hm, 3), s3s = __shfl_down(hs, 3);
        // cross-wave wait (only owners whose continuation crosses the boundary;
        // wave 15 provably never crosses: pc <= 1023 - tid there)
        if (own && pc > 0 && lane + pc >= 64) {
            while (hflag[wv + 1] < trel) __builtin_amdgcn_s_sleep(1);
            __threadfence_block();
        }
        float tm = m, ts = ss;
        if (pc >= 1) {
            const int sl2 = lane + 1;
            const float em = (sl2 >= 64) ? hsm[(wv + 1) * 4 + sl2 - 64] : s1m;
            const float es = (sl2 >= 64) ? hss[(wv + 1) * 4 + sl2 - 64] : s1s;
            LSE_MERGE(tm, ts, em, es);
        }
        if (pc >= 2) {
            const int sl2 = lane + 2;
            const float em = (sl2 >= 64) ? hsm[(wv + 1) * 4 + sl2 - 64] : s2m;
            const float es = (sl2 >= 64) ? hss[(wv + 1) * 4 + sl2 - 64] : s2s;
            LSE_MERGE(tm, ts, em, es);
        }
        if (pc >= 3) {
            const int sl2 = lane + 3;
            const float em = (sl2 >= 64) ? hsm[(wv + 1) * 4 + sl2 - 64] : s3m;
            const float es = (sl2 >= 64) ? hss[(wv + 1) * 4 + sl2 - 64] : s3s;
            LSE_MERGE(tm, ts, em, es);
        }
        if (own) {
            const float mc  = fmaxf(tm, NEGV);
            const float scs = ts * __expf(tm - mc);
            const float v2  = mc + __logf(fmaxf(scs, 1e-30f));
            nxt[tstate] = v2;
            nxt[tdual]  = v2;
        }
        if (d0) { nxt[tid] = c0; nxt[sdual] = c0; }
        __syncthreads();                  // the ONLY barrier per step
        { float* t2 = cur; cur = nxt; nxt = t2; }
        if (pre) {
#pragma unroll
            for (int i = 0; i < 16; ++i) wc[i] = wn[i];
        }
    }

    if (last) {
        const float v = cur[tid] + fin;
        float* red = nxt;   // free buffer
        red[tid] = v;
        __syncthreads();
        for (int off = 512; off > 0; off >>= 1) {
            if (tid < off) red[tid] = fmaxf(red[tid], red[tid + off]);
            __syncthreads();
        }
        const float M = red[0];
        __syncthreads();
        red[tid] = __expf(v - M);
        __syncthreads();
        for (int off = 512; off > 0; off >>= 1) {
            if (tid < off) red[tid] += red[tid + off];
            __syncthreads();
        }
        if (tid == 0) *res = M + __logf(red[0]);
    } else {
        alpha_gl[tid] = cur[tid];
    }
}

// ---------------------------------------------------------------------------
// num forward (r8, passed): CH=2 chunks, pk partial merge, two barriers.
// Not the critical path.
// ---------------------------------------------------------------------------
__device__ void fsm_forward_num(int L, int t0, int Tt, bool first, bool last,
    const float* __restrict__ Wrow0,
    const unsigned* __restrict__ meta_g,
    const int* __restrict__ pbeg_g, const int* __restrict__ padj_g,
    const float* __restrict__ initv, const float* __restrict__ finalv,
    float* __restrict__ alpha_gl, float* __restrict__ res,
    float* alpha_s, float2* pk)
{
    const int tid = threadIdx.x;
    unsigned meta[2];
    meta[0] = meta_g[tid];
    meta[1] = meta_g[NTH + tid];
    const bool sameseg = ((meta[0] >> 16) == (meta[1] >> 16));
    const int slot0 = padj_g[meta[0] >> 16] + tid;
    const bool st = tid < NN;
    int pb0 = 0, pb1 = 0; float fin = 0.f;
    if (st) {
        const float a0 = first ? initv[tid] : alpha_gl[tid];
        alpha_s[tid] = a0;
        alpha_s[NN + (tid ^ ((tid >> 5) & 31))] = a0;
        pb0 = pbeg_g[tid]; pb1 = pbeg_g[tid + 1];
        fin = finalv[tid];
    }
    int tb = L - t0; if (tb > Tt) tb = Tt; if (tb < 0) tb = 0;
    float wc0 = 0.f, wc1 = 0.f;
    if (tb > 0) {
        const float2 v = *(const float2*)(Wrow0 + (size_t)tid * 2);
        wc0 = v.x; wc1 = v.y;
    }
    __syncthreads();

    for (int trel = 0; trel < tb; ++trel) {
        const bool pre = (trel + 1 < tb);
        float wn0 = 0.f, wn1 = 0.f;
        if (pre) {
            const float2 v = *(const float2*)(Wrow0 + (size_t)(trel + 1) * AN + (size_t)tid * 2);
            wn0 = v.x; wn1 = v.y;
        }
        const float s0 = alpha_s[meta[0] & 0xffffu] + wc0;
        const float s1 = alpha_s[meta[1] & 0xffffu] + wc1;
        if (sameseg) {
            const float m = fmaxf(s0, s1);
            pk[slot0] = make_float2(m, __expf(s0 - m) + __expf(s1 - m));
        } else {
            pk[slot0]     = make_float2(s0, 1.f);
            pk[slot0 + 1] = make_float2(s1, 1.f);
        }
        __syncthreads();
        if (st) {
            float v2;
            const int cnt2 = pb1 - pb0;
            if (cnt2 > 0) {
                const float2 P0 = pk[pb0];
                float mm = P0.x, s2 = P0.y;
                for (int q2 = pb0 + 1; q2 < pb1; ++q2) {
                    const float2 Pq = pk[q2];
                    LSE_MERGE(mm, s2, Pq.x, Pq.y);
                }
                const float mc  = fmaxf(mm, NEGV);
                const float scs = s2 * __expf(mm - mc);
                v2 = mc + __logf(fmaxf(scs, 1e-30f));
            } else {
                v2 = NEGV + __logf(1e-30f);
            }
            alpha_s[tid] = v2;
            alpha_s[NN + (tid ^ ((tid >> 5) & 31))] = v2;
        }
        __syncthreads();
        if (pre) { wc0 = wn0; wc1 = wn1; }
    }

    if (last) {
        const float v = st ? (alpha_s[tid] + fin) : -INFINITY;
        float* red = (float*)pk;
        red[tid] = v;
        __syncthreads();
        for (int off = 512; off > 0; off >>= 1) {
            if (tid < off) red[tid] = fmaxf(red[tid], red[tid + off]);
            __syncthreads();
        }
        const float M = red[0];
        __syncthreads();
        red[tid] = __expf(v - M);
        __syncthreads();
        for (int off = 512; off > 0; off >>= 1) {
            if (tid < off) red[tid] += red[tid + off];
            __syncthreads();
        }
        if (tid == 0) *res = M + __logf(red[0]);
    } else if (st) {
        alpha_gl[tid] = alpha_s[tid];
    }
}

// ---------------------------------------------------------------------------
// fused (grid NWG=256): 0..15 den fwd, 16..47 num fwd, 48..255 wprep tile k+1.
// ---------------------------------------------------------------------------
__global__ __launch_bounds__(1024) void fused_kernel(
    const int* __restrict__ seqlen,
    const float* __restrict__ Wd, const float* __restrict__ Wn,
    const unsigned* __restrict__ den_meta,
    const unsigned* __restrict__ den_flg, const unsigned* __restrict__ den_tst,
    const unsigned* __restrict__ den_deg0,
    const float* __restrict__ den_init, const float* __restrict__ den_final,
    const unsigned* __restrict__ num_meta,
    const int* __restrict__ num_pbeg, const int* __restrict__ num_padj,
    const float* __restrict__ num_init, const float* __restrict__ num_final,
    float* __restrict__ alpha_g, float* __restrict__ res,
    int t0, int Tt, int last,
    const float* __restrict__ est,
    const unsigned* __restrict__ pxi_den, const float* __restrict__ wcsr_den,
    const unsigned* __restrict__ pxi_num, const float* __restrict__ wcsr_num,
    float* __restrict__ Wd_next, float* __restrict__ Wn_next)
{
    __shared__ float bufA[2048];
    __shared__ float bufB[2048];
    __shared__ float2 pk[2048];
    __shared__ float row_s[CC];
    __shared__ float hsm[64];
    __shared__ float hss[64];
    __shared__ int   hflag[16];
    const int bid = blockIdx.x;
    const bool first = (t0 == 0);
    if (bid >= 48) {
        if (!last)
            wprep_part(bid - 48, NWG - 48, t0 + Tt, Tt, est,
                       pxi_den, wcsr_den, pxi_num, wcsr_num,
                       Wd_next, Wn_next, row_s);
        return;
    }
    if (bid < 16) {
        const int s = bid >> 3, b = bid & 7;
        const int L = seqlen[b * SS + s];
        fsm_forward_den(L, t0, Tt, first, last != 0,
                        Wd + (size_t)bid * Tt * AD,
                        den_meta, den_flg, den_tst, den_deg0,
                        den_init, den_final,
                        alpha_g + (size_t)bid * 1024, &res[bid],
                        bufA, bufB, hsm, hss, hflag);
    } else {
        const int q = bid - 16;
        const int p = q >> 4, g = q & 15;
        const int s = g >> 3, b = g & 7;
        const int sp = p ? (1 - s) : s;
        const int L = seqlen[b * SS + sp];
        fsm_forward_num(L, t0, Tt, first, last != 0,
                        Wn + (size_t)q * Tt * AN,
                        num_meta + (size_t)g * AN,
                        num_pbeg + (size_t)g * (NN + 1), num_padj + (size_t)g * NN,
                        num_init + (size_t)g * NN, num_final + (size_t)g * NN,
                        alpha_g + (size_t)bid * 1024, &res[16 + q], bufA, pk);
    }
}

// res layout: [0..15] den (s*8+b), [16..31] num perm0, [32..47] num perm1
__global__ void finalize_kernel(const float* __restrict__ res, float* __restrict__ out)
{
    if (threadIdx.x == 0 && blockIdx.x == 0) {
        float loss = 0.f;
        for (int b = 0; b < BB; ++b) {
            const float den = res[b] + res[8 + b];
            const float n0  = res[16 + b] + res[16 + 8 + b];
            const float n1  = res[32 + b] + res[32 + 8 + b];
            const float nm  = fminf(n0, n1);
            loss += -(nm - den);
        }
        out[0] = loss;
    }
}

extern "C" void kernel_launch(void* const* d_in, const int* in_sizes, int n_in,
                              void* d_out, int out_size, void* d_ws, size_t ws_size,
                              hipStream_t stream)
{
    const float* est       = (const float*)d_in[0];
    const int*   seqlen    = (const int*)  d_in[1];
    const int*   den_src   = (const int*)  d_in[2];
    const int*   den_dst   = (const int*)  d_in[3];
    const int*   den_pdf   = (const int*)  d_in[4];
    const float* den_w     = (const float*)d_in[5];
    const float* den_init  = (const float*)d_in[6];
    const float* den_final = (const float*)d_in[7];
    const int*   num_src   = (const int*)  d_in[8];
    const int*   num_dst   = (const int*)  d_in[9];
    const int*   num_pdf   = (const int*)  d_in[10];
    const float* num_w     = (const float*)d_in[11];
    const float* num_init  = (const float*)d_in[12];
    const float* num_final = (const float*)d_in[13];

    char* ws = (char*)d_ws;
    unsigned* den_meta = (unsigned*)(ws + 0);        //  65536 -> 65536
    unsigned* den_pxi  = (unsigned*)(ws + 65536);    //  65536 -> 131072
    float*    den_wcsr = (float*)   (ws + 131072);   //  65536 -> 196608
    unsigned* num_meta = (unsigned*)(ws + 196608);   // 131072 -> 327680
    unsigned* num_pxi  = (unsigned*)(ws + 327680);   // 131072 -> 458752
    float*    num_wcsr = (float*)   (ws + 458752);   // 131072 -> 589824
    int*      num_pbeg = (int*)     (ws + 589824);   //  16448 -> 606272
    int*      num_padj = (int*)     (ws + 606272);   //  16384 -> 622656
    unsigned* den_flg  = (unsigned*)(ws + 622656);   //   4096 -> 626752
    unsigned* den_tst  = (unsigned*)(ws + 626752);   //   4096 -> 630848
    unsigned* den_deg0 = (unsigned*)(ws + 630848);   //    128 -> 630976
    float*    alpha_g  = (float*)   (ws + 630976);   // 196608 -> 827584
    float*    res      = (float*)   (ws + 827584);   //    192 -> 827776
    const size_t fixed = 827904;

    // W' double buffer: per buffer Tt*(16*AD + 32*AN)*4 = Tt*1310720 bytes
    int Tt = 64;
    while (Tt > 4 && fixed + 2ull * (size_t)Tt * 1310720ull > ws_size) Tt >>= 1;
    const size_t wbuf_f = (size_t)Tt * (16 * AD + 32 * AN);
    float* Wd0 = (float*)(ws + fixed);
    float* Wn0 = Wd0 + (size_t)16 * Tt * AD;
    float* Wd1 = Wd0 + wbuf_f;
    float* Wn1 = Wd1 + (size_t)16 * Tt * AD;

    prep_den_kernel<<<1, 1024, 0, stream>>>(den_src, den_dst, den_pdf, den_w,
                                            den_meta, den_pxi, den_wcsr,
                                            den_flg, den_tst, den_deg0);
    prep_kernel<<<16, 256, 0, stream>>>(num_src, num_dst, num_pdf, num_w,
                                        num_meta, num_pxi, num_wcsr,
                                        num_pbeg, num_padj, NN, AN, 1);

    wprep0_kernel<<<256, 1024, 0, stream>>>(est, den_pxi, den_wcsr,
                                            num_pxi, num_wcsr, Wd0, Wn0, 0, Tt);

    const int nt = TT / Tt;
    for (int k = 0; k < nt; ++k) {
        float* WdC = (k & 1) ? Wd1 : Wd0;
        float* WnC = (k & 1) ? Wn1 : Wn0;
        float* WdN = (k & 1) ? Wd0 : Wd1;
        float* WnN = (k & 1) ? Wn0 : Wn1;
        fused_kernel<<<NWG, 1024, 0, stream>>>(seqlen, WdC, WnC,
                                               den_meta, den_flg, den_tst, den_deg0,
                                               den_init, den_final,
                                               num_meta, num_pbeg, num_padj,
                                               num_init, num_final,
                                               alpha_g, res, k * Tt, Tt,
                                               (k == nt - 1) ? 1 : 0,
                                               est, den_pxi, den_wcsr,
                                               num_pxi, num_wcsr, WdN, WnN);
    }

    finalize_kernel<<<1, 64, 0, stream>>>(res, (float*)d_out);
}

// Round 10
// 1275.217 us; speedup vs baseline: 1.7283x; 1.6975x over previous
//
#include <hip/hip_runtime.h>
#include <cstdint>
#include <cstddef>

#define BB 8
#define SS 2
#define TT 512
#define CC 2048
#define ND 1024
#define AD 16384
#define NN 256
#define AN 2048
#define NEGV -1e30f
#define NTH 1024   // fwd block threads == number of arc chunks per graph
#define NWG 256    // fused grid: 16 den + 32 num + 208 wprep workers

// ---------------------------------------------------------------------------
// prep: counting sort of arcs by dst (CSR order) into chunk-transposed SoA
//   meta = gidx | dst<<16   (gidx = LDS gather index into dual-copy alpha)
//   pxi[p] = pdf, wcsr[p] = weight (CSR order, for the W' precompute)
// plus partial-slot tables for the segmented merge:
//   pbeg = excl-scan(npart); padj[j] = pbeg[j] - (rowptr[j] >> LC)
// After the scatter, a two-choice greedy pass assigns each arc to alpha copy0
// (index src, bank src&31) or copy1 (index N + (src ^ ((src>>5)&31))), picking
// per hardware gather group (wave w, slot i == 64 lanes) the copy whose bank
// has the lower load -> near-conflict-free gathers. Value read is identical.
// One block per graph, blockDim.x == N.
// ---------------------------------------------------------------------------
__global__ void prep_kernel(const int* __restrict__ src, const int* __restrict__ dst,
                            const int* __restrict__ pdf, const float* __restrict__ w,
                            unsigned* __restrict__ meta_t, unsigned* __restrict__ pxi,
                            float* __restrict__ wcsr,
                            int* __restrict__ pbeg, int* __restrict__ padj,
                            int N, int A, int LC)
{
    __shared__ int cnt[1024];
    __shared__ int pos[1024];
    __shared__ unsigned char gcnt[8192];
    const int g = blockIdx.x;
    src += (size_t)g * A; dst += (size_t)g * A; pdf += (size_t)g * A; w += (size_t)g * A;
    meta_t += (size_t)g * A; pxi += (size_t)g * A; wcsr += (size_t)g * A;
    pbeg += (size_t)g * (N + 1); padj += (size_t)g * N;
    const int tid = threadIdx.x;
    cnt[tid] = 0;
    __syncthreads();
    for (int a = tid; a < A; a += blockDim.x) atomicAdd(&cnt[dst[a]], 1);
    __syncthreads();
    const int deg = cnt[tid];
    pos[tid] = deg;
    __syncthreads();
    for (int off = 1; off < blockDim.x; off <<= 1) {
        int add = (tid >= off) ? pos[tid - off] : 0;
        __syncthreads();
        pos[tid] += add;
        __syncthreads();
    }
    const int r0 = pos[tid] - deg;
    const int np = deg ? (((r0 + deg - 1) >> LC) - (r0 >> LC) + 1) : 0;
    __syncthreads();
    pos[tid] = np;
    __syncthreads();
    for (int off = 1; off < blockDim.x; off <<= 1) {
        int add = (tid >= off) ? pos[tid - off] : 0;
        __syncthreads();
        pos[tid] += add;
        __syncthreads();
    }
    const int pexcl = pos[tid] - np;
    pbeg[tid] = pexcl;
    if (tid == blockDim.x - 1) pbeg[N] = pexcl + np;
    padj[tid] = pexcl - (r0 >> LC);
    cnt[tid] = r0;
    __syncthreads();
    for (int a = tid; a < A; a += blockDim.x) {
        const int d2 = dst[a];
        const int p = atomicAdd(&cnt[d2], 1);
        const int l = p >> LC;
        const int i = p & ((1 << LC) - 1);
        meta_t[(size_t)i * NTH + l] = (unsigned)src[a] | ((unsigned)d2 << 16);
        pxi[p] = (unsigned)pdf[a];
        wcsr[p] = w[a];
    }
    __syncthreads();
    const int CH = 1 << LC;
    const int ngrp = (NTH / 64) * CH;
    if (tid < ngrp) {
        unsigned char* cb = &gcnt[tid * 32];
        for (int b = 0; b < 32; ++b) cb[b] = 0;
        const int i = tid & (CH - 1);
        const int w2 = tid >> LC;
        for (int lane = 0; lane < 64; ++lane) {
            const size_t idx = (size_t)i * NTH + (w2 * 64 + lane);
            const unsigned mt = meta_t[idx];
            const unsigned sv = mt & 0xffffu;
            const unsigned alt = sv ^ ((sv >> 5) & 31u);
            const int b0 = (int)(sv & 31u), b1 = (int)(alt & 31u);
            unsigned gx;
            if (cb[b1] < cb[b0]) { cb[b1]++; gx = (unsigned)N + alt; }
            else                 { cb[b0]++; gx = sv; }
            meta_t[idx] = (mt & 0xffff0000u) | gx;
        }
    }
}

// ---------------------------------------------------------------------------
// W' production for one time tile: W'[inst][trel][pos] = llh[t][pdf] + w
// (weight folded in — verified passing in r8/r9). Row staged in LDS;
// coalesced float4 reads/writes. Layout inst-major: W'[inst][trel][arc].
// ---------------------------------------------------------------------------
__device__ void wprep_part(int ub, int nb, int t0, int Tt, const float* __restrict__ est,
                           const unsigned* __restrict__ pxi_den,
                           const float* __restrict__ wcsr_den,
                           const unsigned* __restrict__ pxi_num,
                           const float* __restrict__ wcsr_num,
                           float* __restrict__ Wd, float* __restrict__ Wn,
                           float* row_s)
{
    const int tid = threadIdx.x;
    const int nden = 16 * Tt;
    const int total = nden + 32 * Tt;
    for (int u = ub; u < total; u += nb) {
        __syncthreads();   // previous unit's row_s readers done
        const float* row; const unsigned* pxi; const float* wcs; float* out; int n4;
        if (u < nden) {
            const int inst = u / Tt, trel = u - inst * Tt;
            const int s = inst >> 3, b = inst & 7;
            row = est + ((size_t)(b * SS + s) * TT + (t0 + trel)) * CC;
            pxi = pxi_den; wcs = wcsr_den;
            out = Wd + ((size_t)inst * Tt + trel) * AD;
            n4 = AD >> 2;
        } else {
            const int v = u - nden;
            const int inst = v / Tt, trel = v - inst * Tt;   // inst = p*16+g
            const int gg = inst & 15, p = inst >> 4;
            const int s = gg >> 3, b = gg & 7;
            const int sp = p ? (1 - s) : s;
            row = est + ((size_t)(b * SS + sp) * TT + (t0 + trel)) * CC;
            pxi = pxi_num + (size_t)gg * AN; wcs = wcsr_num + (size_t)gg * AN;
            out = Wn + ((size_t)inst * Tt + trel) * AN;
            n4 = AN >> 2;
        }
        row_s[tid] = row[tid]; row_s[tid + 1024] = row[tid + 1024];
        __syncthreads();
        const uint4* p4 = (const uint4*)pxi;
        const float4* w4 = (const float4*)wcs;
        float4* o4 = (float4*)out;
        for (int k = tid; k < n4; k += 1024) {
            const uint4 pp = p4[k];
            const float4 ww = w4[k];
            o4[k] = make_float4(row_s[pp.x] + ww.x, row_s[pp.y] + ww.y,
                                row_s[pp.z] + ww.z, row_s[pp.w] + ww.w);
        }
    }
}

__global__ __launch_bounds__(1024) void wprep0_kernel(
    const float* __restrict__ est,
    const unsigned* __restrict__ pxi_den, const float* __restrict__ wcsr_den,
    const unsigned* __restrict__ pxi_num, const float* __restrict__ wcsr_num,
    float* __restrict__ Wd, float* __restrict__ Wn, int t0, int Tt)
{
    __shared__ float row_s[CC];
    wprep_part(blockIdx.x, gridDim.x, t0, Tt, est, pxi_den, wcsr_den,
               pxi_num, wcsr_num, Wd, Wn, row_s);
}

template<int CH>
__device__ inline void load_w_row(const float* __restrict__ p, float* dst)
{
    if constexpr (CH == 16) {
        const float4* p4 = (const float4*)p;
        const float4 a = p4[0], b = p4[1], c = p4[2], d = p4[3];
        dst[0]=a.x;  dst[1]=a.y;  dst[2]=a.z;  dst[3]=a.w;
        dst[4]=b.x;  dst[5]=b.y;  dst[6]=b.z;  dst[7]=b.w;
        dst[8]=c.x;  dst[9]=c.y;  dst[10]=c.z; dst[11]=c.w;
        dst[12]=d.x; dst[13]=d.y; dst[14]=d.z; dst[15]=d.w;
    } else {
        const float2 v = *(const float2*)p;
        dst[0] = v.x; dst[1] = v.y;
    }
}

// ---------------------------------------------------------------------------
// FSM forward over one time tile [t0, t0+Tt)  (r7 structure verbatim, with
// arc weight folded into the W' stream -> no wreg[] array):
//   phase 1 (two-pass segmented LSE): sc[] computed independently; forward
//     running-max scan with segment reset; backward select scan gives each
//     arc its segment max; independent exps; ordered sum scan emits (m, sum)
//     partials to consecutive LDS slots.
//   phase 2: owner merges its <=4 partials (batch-loaded, clamped), writes
//     both alpha copies. Reference semantics preserved:
//       mc=max(m,NEG); s'=s*exp(m-mc); new=mc+log(max(s',1e-30))
// alpha persists in global between tiles; final tile does the LSE reduce.
// ---------------------------------------------------------------------------
template<int CH>
__device__ void fsm_forward_tile(int N, int L, int t0, int Tt, bool first, bool last,
    const float* __restrict__ Wrow0, int wstride,
    const unsigned* __restrict__ meta_g,
    const int* __restrict__ pbeg_g, const int* __restrict__ padj_g,
    const float* __restrict__ initv, const float* __restrict__ finalv,
    float* __restrict__ alpha_gl, float* __restrict__ res,
    float* alpha_s, float2* pk)
{
    const int tid = threadIdx.x;
    // arc records -> registers (coalesced: element i of thread l at i*1024+l)
    unsigned meta[CH];
#pragma unroll
    for (int i = 0; i < CH; ++i) meta[i] = meta_g[i * NTH + tid];
    unsigned segmask = 0;   // bit CH-1 always set
#pragma unroll
    for (int i = 0; i < CH; ++i) {
        const int di = (int)(meta[i] >> 16);
        const int dn = (i + 1 < CH) ? (int)(meta[i + 1] >> 16) : -1;
        if (di != dn) segmask |= (1u << i);
    }
    const int slot0 = padj_g[meta[0] >> 16] + tid;  // slots consecutive per thread
    const bool st = tid < N;
    int pb0 = 0, pb1 = 0; float fin = 0.f;
    if (st) {
        const float a0 = first ? initv[tid] : alpha_gl[tid];
        alpha_s[tid] = a0;
        alpha_s[N + (tid ^ ((tid >> 5) & 31))] = a0;   // dual copy (free write)
        pb0 = pbeg_g[tid]; pb1 = pbeg_g[tid + 1];
        fin = finalv[tid];
    }
    int tb = L - t0; if (tb > Tt) tb = Tt; if (tb < 0) tb = 0;
    float wc[CH];
    if (tb > 0) load_w_row<CH>(Wrow0 + (size_t)tid * CH, wc);
    __syncthreads();

    for (int trel = 0; trel < tb; ++trel) {
        const bool pre = (trel + 1 < tb);
        float wn[CH];
        if (pre)   // prefetch next step's W'; latency hides under phase 1+2
            load_w_row<CH>(Wrow0 + (size_t)(trel + 1) * wstride + (size_t)tid * CH, wn);
        // phase 1: batch gathers, then two-pass segmented logsumexp
        float av[CH];
#pragma unroll
        for (int i = 0; i < CH; ++i)
            av[i] = alpha_s[meta[i] & 0xffffu];
        float sc[CH];
#pragma unroll
        for (int i = 0; i < CH; ++i)
            sc[i] = av[i] + wc[i];          // wc = weight + llh (folded)
        // forward running max with reset at segment ends
        float pm[CH];
        {
            float m = -INFINITY;
#pragma unroll
            for (int i = 0; i < CH; ++i) {
                m = fmaxf(m, sc[i]);
                pm[i] = m;
                if (segmask & (1u << i)) m = -INFINITY;
            }
        }
        // backward: per-arc segment max (bit CH-1 always set)
        float sm[CH];
        sm[CH - 1] = pm[CH - 1];
#pragma unroll
        for (int i = CH - 2; i >= 0; --i)
            sm[i] = (segmask & (1u << i)) ? pm[i] : sm[i + 1];
        // independent exps + ordered segmented sum, emit partials
        {
            float ssn = 0.f;
            int sl = slot0;
#pragma unroll
            for (int i = 0; i < CH; ++i) {
                ssn += __expf(sc[i] - sm[i]);
                if (segmask & (1u << i)) {
                    pk[sl] = make_float2(sm[i], ssn); ++sl;
                    ssn = 0.f;
                }
            }
        }
        __syncthreads();                                 // partials + alpha reads done
        // phase 2: owner merges partials (slot order == arc order), batch-loaded
        if (st) {
            float v2;
            const int cnt = pb1 - pb0;
            if (cnt > 0) {
                const float2 P0 = pk[pb0];
                const float2 P1 = pk[cnt > 1 ? pb0 + 1 : pb0];
                const float2 P2 = pk[cnt > 2 ? pb0 + 2 : pb0];
                const float2 P3 = pk[cnt > 3 ? pb0 + 3 : pb0];
                float mm = P0.x, s2 = P0.y;
                if (cnt > 1) {
                    const float d = P1.x - mm; const float e = __expf(-fabsf(d));
                    if (d > 0.f) { s2 = s2 * e + P1.y; mm = P1.x; } else { s2 += P1.y * e; }
                }
                if (cnt > 2) {
                    const float d = P2.x - mm; const float e = __expf(-fabsf(d));
                    if (d > 0.f) { s2 = s2 * e + P2.y; mm = P2.x; } else { s2 += P2.y * e; }
                }
                if (cnt > 3) {
                    const float d = P3.x - mm; const float e = __expf(-fabsf(d));
                    if (d > 0.f) { s2 = s2 * e + P3.y; mm = P3.x; } else { s2 += P3.y * e; }
                }
                for (int q2 = pb0 + 4; q2 < pb1; ++q2) {  // rare
                    const float2 Pq = pk[q2];
                    const float d = Pq.x - mm; const float e = __expf(-fabsf(d));
                    if (d > 0.f) { s2 = s2 * e + Pq.y; mm = Pq.x; } else { s2 += Pq.y * e; }
                }
                const float mc  = fmaxf(mm, NEGV);
                const float scs = s2 * __expf(mm - mc);
                v2 = mc + __logf(fmaxf(scs, 1e-30f));
            } else {
                v2 = NEGV + __logf(1e-30f);              // no in-arcs (matches ref)
            }
            alpha_s[tid] = v2;
            alpha_s[N + (tid ^ ((tid >> 5) & 31))] = v2;
        }
        __syncthreads();
        if (pre) {
#pragma unroll
            for (int i = 0; i < CH; ++i) wc[i] = wn[i];
        }
    }

    if (last) {
        // logsumexp(alpha + final) over N states, block-wide tree reduce
        const float v = st ? (alpha_s[tid] + fin) : -INFINITY;
        float* red = (float*)pk;
        red[tid] = v;
        __syncthreads();
        for (int off = 512; off > 0; off >>= 1) {
            if (tid < off) red[tid] = fmaxf(red[tid], red[tid + off]);
            __syncthreads();
        }
        const float M = red[0];
        __syncthreads();
        red[tid] = __expf(v - M);
        __syncthreads();
        for (int off = 512; off > 0; off >>= 1) {
            if (tid < off) red[tid] += red[tid + off];
            __syncthreads();
        }
        if (tid == 0) *res = M + __logf(red[0]);
    } else if (st) {
        alpha_gl[tid] = alpha_s[tid];
    }
}

// ---------------------------------------------------------------------------
// fused (grid NWG=256): blocks 0..15 den fwd (tile k); 16..47 num fwd (tile
// k); 48..255 produce W' for tile k+1 across 208 CUs (hidden under den time).
// ---------------------------------------------------------------------------
__global__ __launch_bounds__(1024) void fused_kernel(
    const int* __restrict__ seqlen,
    const float* __restrict__ Wd, const float* __restrict__ Wn,
    const unsigned* __restrict__ den_meta,
    const int* __restrict__ den_pbeg, const int* __restrict__ den_padj,
    const float* __restrict__ den_init, const float* __restrict__ den_final,
    const unsigned* __restrict__ num_meta,
    const int* __restrict__ num_pbeg, const int* __restrict__ num_padj,
    const float* __restrict__ num_init, const float* __restrict__ num_final,
    float* __restrict__ alpha_g, float* __restrict__ res,
    int t0, int Tt, int last,
    const float* __restrict__ est,
    const unsigned* __restrict__ pxi_den, const float* __restrict__ wcsr_den,
    const unsigned* __restrict__ pxi_num, const float* __restrict__ wcsr_num,
    float* __restrict__ Wd_next, float* __restrict__ Wn_next)
{
    __shared__ float alpha[2048];   // dual-copy alpha (den: 2*1024)
    __shared__ float2 pk[2048];     // partials; reused as reduce buffer
    __shared__ float row_s[CC];     // wprep staging (worker blocks only)
    const int bid = blockIdx.x;
    const bool first = (t0 == 0);
    if (bid >= 48) {
        if (!last)   // produce next tile's W', spread over 208 CUs
            wprep_part(bid - 48, NWG - 48, t0 + Tt, Tt, est,
                       pxi_den, wcsr_den, pxi_num, wcsr_num,
                       Wd_next, Wn_next, row_s);
        return;
    }
    if (bid < 16) {
        const int s = bid >> 3, b = bid & 7;
        const int L = seqlen[b * SS + s];
        fsm_forward_tile<16>(ND, L, t0, Tt, first, last != 0,
                             Wd + (size_t)bid * Tt * AD, AD,
                             den_meta, den_pbeg, den_padj,
                             den_init, den_final,
                             alpha_g + (size_t)bid * 1024, &res[bid], alpha, pk);
    } else {
        const int q = bid - 16;
        const int p = q >> 4, g = q & 15;
        const int s = g >> 3, b = g & 7;
        const int sp = p ? (1 - s) : s;
        const int L = seqlen[b * SS + sp];
        fsm_forward_tile<2>(NN, L, t0, Tt, first, last != 0,
                            Wn + (size_t)q * Tt * AN, AN,
                            num_meta + (size_t)g * AN,
                            num_pbeg + (size_t)g * (NN + 1), num_padj + (size_t)g * NN,
                            num_init + (size_t)g * NN, num_final + (size_t)g * NN,
                            alpha_g + (size_t)bid * 1024, &res[16 + q], alpha, pk);
    }
}

// res layout: [0..15] den (s*8+b), [16..31] num perm0, [32..47] num perm1
__global__ void finalize_kernel(const float* __restrict__ res, float* __restrict__ out)
{
    if (threadIdx.x == 0 && blockIdx.x == 0) {
        float loss = 0.f;
        for (int b = 0; b < BB; ++b) {
            const float den = res[b] + res[8 + b];
            const float n0  = res[16 + b] + res[16 + 8 + b];
            const float n1  = res[32 + b] + res[32 + 8 + b];
            const float nm  = fminf(n0, n1);
            loss += -(nm - den);
        }
        out[0] = loss;
    }
}

extern "C" void kernel_launch(void* const* d_in, const int* in_sizes, int n_in,
                              void* d_out, int out_size, void* d_ws, size_t ws_size,
                              hipStream_t stream)
{
    const float* est       = (const float*)d_in[0];
    const int*   seqlen    = (const int*)  d_in[1];
    const int*   den_src   = (const int*)  d_in[2];
    const int*   den_dst   = (const int*)  d_in[3];
    const int*   den_pdf   = (const int*)  d_in[4];
    const float* den_w     = (const float*)d_in[5];
    const float* den_init  = (const float*)d_in[6];
    const float* den_final = (const float*)d_in[7];
    const int*   num_src   = (const int*)  d_in[8];
    const int*   num_dst   = (const int*)  d_in[9];
    const int*   num_pdf   = (const int*)  d_in[10];
    const float* num_w     = (const float*)d_in[11];
    const float* num_init  = (const float*)d_in[12];
    const float* num_final = (const float*)d_in[13];

    char* ws = (char*)d_ws;
    unsigned* den_meta = (unsigned*)(ws + 0);        //  65536 -> 65536
    unsigned* den_pxi  = (unsigned*)(ws + 65536);    //  65536 -> 131072
    float*    den_wcsr = (float*)   (ws + 131072);   //  65536 -> 196608
    unsigned* num_meta = (unsigned*)(ws + 196608);   // 131072 -> 327680
    unsigned* num_pxi  = (unsigned*)(ws + 327680);   // 131072 -> 458752
    float*    num_wcsr = (float*)   (ws + 458752);   // 131072 -> 589824
    int*      num_pbeg = (int*)     (ws + 589824);   //  16448 -> 606272
    int*      num_padj = (int*)     (ws + 606272);   //  16384 -> 622656
    int*      den_pbeg = (int*)     (ws + 622656);   //   4100 -> 626756 (pad 626816)
    int*      den_padj = (int*)     (ws + 626816);   //   4096 -> 630912
    float*    alpha_g  = (float*)   (ws + 630912);   // 196608 -> 827520
    float*    res      = (float*)   (ws + 827520);   //    192 -> 827712
    const size_t fixed = 827904;

    // W' double buffer: per buffer Tt*(16*AD + 32*AN)*4 = Tt*1310720 bytes
    int Tt = 64;
    while (Tt > 4 && fixed + 2ull * (size_t)Tt * 1310720ull > ws_size) Tt >>= 1;
    const size_t wbuf_f = (size_t)Tt * (16 * AD + 32 * AN);
    float* Wd0 = (float*)(ws + fixed);
    float* Wn0 = Wd0 + (size_t)16 * Tt * AD;
    float* Wd1 = Wd0 + wbuf_f;
    float* Wn1 = Wd1 + (size_t)16 * Tt * AD;

    // den: CH=16 (LC=4); num: CH=2 (LC=1)
    prep_kernel<<<1, 1024, 0, stream>>>(den_src, den_dst, den_pdf, den_w,
                                        den_meta, den_pxi, den_wcsr,
                                        den_pbeg, den_padj, ND, AD, 4);
    prep_kernel<<<16, 256, 0, stream>>>(num_src, num_dst, num_pdf, num_w,
                                        num_meta, num_pxi, num_wcsr,
                                        num_pbeg, num_padj, NN, AN, 1);

    wprep0_kernel<<<256, 1024, 0, stream>>>(est, den_pxi, den_wcsr,
                                            num_pxi, num_wcsr, Wd0, Wn0, 0, Tt);

    const int nt = TT / Tt;
    for (int k = 0; k < nt; ++k) {
        float* WdC = (k & 1) ? Wd1 : Wd0;
        float* WnC = (k & 1) ? Wn1 : Wn0;
        float* WdN = (k & 1) ? Wd0 : Wd1;
        float* WnN = (k & 1) ? Wn0 : Wn1;
        fused_kernel<<<NWG, 1024, 0, stream>>>(seqlen, WdC, WnC,
                                               den_meta, den_pbeg, den_padj,
                                               den_init, den_final,
                                               num_meta, num_pbeg, num_padj,
                                               num_init, num_final,
                                               alpha_g, res, k * Tt, Tt,
                                               (k == nt - 1) ? 1 : 0,
                                               est, den_pxi, den_wcsr,
                                               num_pxi, num_wcsr, WdN, WnN);
    }

    finalize_kernel<<<1, 64, 0, stream>>>(res, (float*)d_out);
}